// Round 10
// baseline (593.811 us; speedup 1.0000x reference)
//
#include <hip/hip_runtime.h>

#define N_M 100000
#define N_A 20000
#define E_C 1600000
#define E_K 800000
#define CH 2048
#define CAP_C 208192   // E_C/8 + 8192 slack (~19 sigma for uniform dst)
#define CAP_K 108192   // E_K/8 + 8192

typedef __attribute__((ext_vector_type(8)))  short  short8_t;
typedef __attribute__((ext_vector_type(8)))  unsigned short ushort8_t;
typedef __attribute__((ext_vector_type(4)))  unsigned short ushort4_t;
typedef __attribute__((ext_vector_type(4)))  float  f32x4;

__device__ __forceinline__ unsigned short f2b(float f) {   // RNE f32->bf16
    unsigned u = __float_as_uint(f);
    return (unsigned short)((u + 0x7fffu + ((u >> 16) & 1u)) >> 16);
}
__device__ __forceinline__ float b2f(unsigned short h) {
    return __uint_as_float((unsigned)h << 16);
}

// =================== casts ===================
__global__ __launch_bounds__(256) void cast_f32_bf16(const float* __restrict__ in,
                                                     unsigned short* __restrict__ out, int n) {
    int i = (blockIdx.x * 256 + threadIdx.x) * 4;
    if (i >= n) return;
    float4 v = *(const float4*)(in + i);
    ushort4_t o; o.x = f2b(v.x); o.y = f2b(v.y); o.z = f2b(v.z); o.w = f2b(v.w);
    *(ushort4_t*)(out + i) = o;
}

__global__ __launch_bounds__(256) void cast_weights(
    const float* rc0, const float* oc0, const float* rk0, const float* ok0,
    const float* rk1, const float* ok1, unsigned short* __restrict__ wb) {
    int i = (blockIdx.x * 256 + threadIdx.x) * 4;
    if (i >= 98304) return;
    const float* src; int off;
    if      (i < 8192)  { src = rc0; off = 0; }
    else if (i < 16384) { src = oc0; off = 8192; }
    else if (i < 24576) { src = rk0; off = 16384; }
    else if (i < 32768) { src = ok0; off = 24576; }
    else if (i < 65536) { src = rk1; off = 32768; }
    else                { src = ok1; off = 65536; }
    float4 v = *(const float4*)(src + (i - off));
    ushort4_t o; o.x = f2b(v.x); o.y = f2b(v.y); o.z = f2b(v.z); o.w = f2b(v.w);
    *(ushort4_t*)(wb + i) = o;
}

// =================== two-pass bucketed CSR build ===================
__global__ __launch_bounds__(256) void bucket_pass_t(
    const int* __restrict__ dst, const int* __restrict__ src,
    const float* __restrict__ w, int* __restrict__ bdst, int2* __restrict__ bsw,
    int* __restrict__ gcur, int nE, int NPP, int CAP) {
    __shared__ int cnt[8], base[8], off[8];
    int t = threadIdx.x;
    if (t < 8) { cnt[t] = 0; off[t] = 0; }
    __syncthreads();
    int e0 = blockIdx.x * CH + t;
    int d[8], s[8], p[8]; float ww[8];
    #pragma unroll
    for (int k = 0; k < 8; ++k) {
        int e = e0 + k * 256;
        if (e < nE) {
            d[k]  = __builtin_nontemporal_load(dst + e);
            s[k]  = __builtin_nontemporal_load(src + e);
            ww[k] = __builtin_nontemporal_load(w + e);
            p[k]  = d[k] / NPP;
            atomicAdd(&cnt[p[k]], 1);
        } else p[k] = -1;
    }
    __syncthreads();
    if (t < 8) base[t] = atomicAdd(&gcur[t], cnt[t]);
    __syncthreads();
    #pragma unroll
    for (int k = 0; k < 8; ++k) {
        if (p[k] >= 0) {
            int pos = base[p[k]] + atomicAdd(&off[p[k]], 1);
            if (pos < CAP) {                       // memory-safety guard
                bdst[p[k] * CAP + pos] = d[k];
                bsw [p[k] * CAP + pos] = make_int2(s[k], __float_as_int(ww[k]));
            }
        }
    }
}

__global__ __launch_bounds__(256) void hist_bkt(const int* __restrict__ bdst,
                                                const int* __restrict__ gcur,
                                                int* __restrict__ deg, int CAP) {
    int part = blockIdx.x & 7, seg = blockIdx.x >> 3;
    int n = min(gcur[part], CAP);
    int i = seg * CH + threadIdx.x;
    #pragma unroll
    for (int k = 0; k < 8; ++k) {
        int idx = i + k * 256;
        if (idx < n) atomicAdd(&deg[bdst[part * CAP + idx]], 1);
    }
}

__global__ __launch_bounds__(256) void fill_bkt(const int* __restrict__ bdst,
                                                const int2* __restrict__ bsw,
                                                const int* __restrict__ gcur,
                                                int* __restrict__ cursor,
                                                int2* __restrict__ csr_sw, int CAP) {
    int part = blockIdx.x & 7, seg = blockIdx.x >> 3;
    int n = min(gcur[part], CAP);
    int i = seg * CH + threadIdx.x;
    #pragma unroll
    for (int k = 0; k < 8; ++k) {
        int idx = i + k * 256;
        if (idx < n) {
            int d = bdst[part * CAP + idx];
            int pos = atomicAdd(&cursor[d], 1);
            csr_sw[pos] = bsw[part * CAP + idx];
        }
    }
}

// =================== multi-block exclusive scan ===================
__global__ __launch_bounds__(256) void scan_p1(const int* __restrict__ deg,
                                               int* __restrict__ partial, int n) {
    __shared__ int red[256];
    int base = blockIdx.x * CH + threadIdx.x;
    int s = 0;
    #pragma unroll
    for (int k = 0; k < 8; ++k) { int i = base + k * 256; if (i < n) s += deg[i]; }
    red[threadIdx.x] = s; __syncthreads();
    for (int off = 128; off > 0; off >>= 1) {
        if (threadIdx.x < off) red[threadIdx.x] += red[threadIdx.x + off];
        __syncthreads();
    }
    if (threadIdx.x == 0) partial[blockIdx.x] = red[0];
}

__global__ __launch_bounds__(64) void scan_p2(int* __restrict__ partial,
                                              int* __restrict__ rowptr_end, int P) {
    int lane = threadIdx.x;
    int v = (lane < P) ? partial[lane] : 0;
    int incl = v;
    for (int off = 1; off < 64; off <<= 1) {
        int t = __shfl_up(incl, off);
        if (lane >= off) incl += t;
    }
    if (lane < P) partial[lane] = incl - v;
    if (lane == 63) *rowptr_end = incl;
}

__global__ __launch_bounds__(256) void scan_p3(const int* __restrict__ deg,
                                               const int* __restrict__ partial,
                                               int* __restrict__ rowptr,
                                               int* __restrict__ cursor, int n) {
    __shared__ int buf[256];
    int base = blockIdx.x * CH;
    int v[8]; int lsum = 0;
    #pragma unroll
    for (int k = 0; k < 8; ++k) {
        int i = base + threadIdx.x * 8 + k;
        v[k] = (i < n) ? deg[i] : 0; lsum += v[k];
    }
    buf[threadIdx.x] = lsum; __syncthreads();
    for (int off = 1; off < 256; off <<= 1) {
        int t = (threadIdx.x >= off) ? buf[threadIdx.x - off] : 0;
        __syncthreads(); buf[threadIdx.x] += t; __syncthreads();
    }
    int excl = buf[threadIdx.x] - lsum + partial[blockIdx.x];
    #pragma unroll
    for (int k = 0; k < 8; ++k) {
        int i = base + threadIdx.x * 8 + k;
        if (i < n) { rowptr[i] = excl; cursor[i] = excl; }
        excl += v[k];
    }
}

// =================== gather aggregations (bf16 features) ===================
__global__ __launch_bounds__(256) void agg_sum_d64_b(
    const unsigned short* __restrict__ x, const int2* __restrict__ csr_sw,
    const int* __restrict__ rowptr, unsigned short* __restrict__ out, int n) {
    int gw = blockIdx.x * 4 + (threadIdx.x >> 6);
    int lane = threadIdx.x & 63;
    if (gw >= n) return;
    int j = rowptr[gw], end = rowptr[gw + 1];
    float acc = 0.f;
    for (; j + 4 <= end; j += 4) {
        int2 e0 = csr_sw[j], e1 = csr_sw[j+1], e2 = csr_sw[j+2], e3 = csr_sw[j+3];
        float v0 = b2f(x[(size_t)e0.x * 64 + lane]);
        float v1 = b2f(x[(size_t)e1.x * 64 + lane]);
        float v2 = b2f(x[(size_t)e2.x * 64 + lane]);
        float v3 = b2f(x[(size_t)e3.x * 64 + lane]);
        acc = fmaf(v0, __int_as_float(e0.y), acc);
        acc = fmaf(v1, __int_as_float(e1.y), acc);
        acc = fmaf(v2, __int_as_float(e2.y), acc);
        acc = fmaf(v3, __int_as_float(e3.y), acc);
    }
    for (; j < end; ++j) {
        int2 e = csr_sw[j];
        acc = fmaf(b2f(x[(size_t)e.x * 64 + lane]), __int_as_float(e.y), acc);
    }
    out[(size_t)gw * 64 + lane] = f2b(acc);
}

__global__ __launch_bounds__(256) void agg_max_d64_b(
    const unsigned short* __restrict__ x, const int2* __restrict__ csr_sw,
    const int* __restrict__ rowptr, unsigned short* __restrict__ out, int n) {
    int gw = blockIdx.x * 4 + (threadIdx.x >> 6);
    int lane = threadIdx.x & 63;
    if (gw >= n) return;
    int beg = rowptr[gw], end = rowptr[gw + 1];
    float acc = -INFINITY;
    int j = beg;
    for (; j + 4 <= end; j += 4) {
        int2 e0 = csr_sw[j], e1 = csr_sw[j+1], e2 = csr_sw[j+2], e3 = csr_sw[j+3];
        acc = fmaxf(acc, b2f(x[(size_t)e0.x * 64 + lane]) * __int_as_float(e0.y));
        acc = fmaxf(acc, b2f(x[(size_t)e1.x * 64 + lane]) * __int_as_float(e1.y));
        acc = fmaxf(acc, b2f(x[(size_t)e2.x * 64 + lane]) * __int_as_float(e2.y));
        acc = fmaxf(acc, b2f(x[(size_t)e3.x * 64 + lane]) * __int_as_float(e3.y));
    }
    for (; j < end; ++j) {
        int2 e = csr_sw[j];
        acc = fmaxf(acc, b2f(x[(size_t)e.x * 64 + lane]) * __int_as_float(e.y));
    }
    if (beg == end) acc = 0.f;
    out[(size_t)gw * 64 + lane] = f2b(acc);
}

__global__ __launch_bounds__(256) void agg_max_d128_b(
    const unsigned short* __restrict__ x, const int2* __restrict__ csr_sw,
    const int* __restrict__ rowptr, unsigned short* __restrict__ out, int n) {
    int gw = blockIdx.x * 4 + (threadIdx.x >> 6);
    int lane = threadIdx.x & 63;
    if (gw >= n) return;
    int beg = rowptr[gw], end = rowptr[gw + 1];
    float ax = -INFINITY, ay = -INFINITY;
    int j = beg;
    for (; j + 2 <= end; j += 2) {
        int2 e0 = csr_sw[j], e1 = csr_sw[j+1];
        float w0 = __int_as_float(e0.y), w1 = __int_as_float(e1.y);
        unsigned v0 = ((const unsigned*)(x + (size_t)e0.x * 128))[lane];
        unsigned v1 = ((const unsigned*)(x + (size_t)e1.x * 128))[lane];
        ax = fmaxf(ax, b2f((unsigned short)(v0 & 0xffff)) * w0);
        ay = fmaxf(ay, b2f((unsigned short)(v0 >> 16)) * w0);
        ax = fmaxf(ax, b2f((unsigned short)(v1 & 0xffff)) * w1);
        ay = fmaxf(ay, b2f((unsigned short)(v1 >> 16)) * w1);
    }
    for (; j < end; ++j) {
        int2 e = csr_sw[j];
        float ww = __int_as_float(e.y);
        unsigned v = ((const unsigned*)(x + (size_t)e.x * 128))[lane];
        ax = fmaxf(ax, b2f((unsigned short)(v & 0xffff)) * ww);
        ay = fmaxf(ay, b2f((unsigned short)(v >> 16)) * ww);
    }
    if (beg == end) { ax = 0.f; ay = 0.f; }
    ((unsigned*)(out + (size_t)gw * 128))[lane] =
        (unsigned)f2b(ax) | ((unsigned)f2b(ay) << 16);
}

// =================== MFMA dual-GEMM + bias + leaky ===================
template <int K1, int K2, bool OBF>
__global__ __launch_bounds__(256) void dual_gemm_mfma(
    const unsigned short* __restrict__ A1, const unsigned short* __restrict__ A2,
    const unsigned short* __restrict__ B1, const unsigned short* __restrict__ B2,
    const float* __restrict__ bias, void* __restrict__ out, int M, int N) {
    constexpr int KTOT = K1 + K2;
    constexpr int LB = KTOT + 8;
    __shared__ __align__(16) unsigned short sA[128 * 40];
    __shared__ __align__(16) unsigned short sBT[64 * LB];

    const int tid = threadIdx.x;
    const int lane = tid & 63, wid = tid >> 6;
    const int wm = wid >> 1, wn = wid & 1;
    const int bm0 = blockIdx.y * 128, n0 = blockIdx.x * 64;

    for (int idx = tid; idx < KTOT * 64; idx += 256) {
        int k = idx >> 6, n = idx & 63;
        unsigned short v = (k < K1) ? B1[k * N + n0 + n] : B2[(k - K1) * N + n0 + n];
        sBT[n * LB + k] = v;
    }

    f32x4 acc[4][2];
    #pragma unroll
    for (int i = 0; i < 4; ++i)
        #pragma unroll
        for (int j = 0; j < 2; ++j)
            acc[i][j] = (f32x4){0.f, 0.f, 0.f, 0.f};

    const int kk = (lane >> 4) * 8;
    const int l15 = lane & 15;

    for (int k0 = 0; k0 < KTOT; k0 += 32) {
        __syncthreads();
        #pragma unroll
        for (int i = 0; i < 2; ++i) {
            int v = tid + i * 256;
            int row = v >> 2, kv = (v & 3) * 8;
            int gm = bm0 + row, gk = k0 + kv;
            ushort8_t val = (ushort8_t)0;
            if (gm < M) {
                const unsigned short* src = (gk < K1)
                    ? (A1 + (size_t)gm * K1 + gk)
                    : (A2 + (size_t)gm * K2 + (gk - K1));
                val = *(const ushort8_t*)src;
            }
            *(ushort8_t*)(sA + row * 40 + kv) = val;
        }
        __syncthreads();

        short8_t bfr[2];
        #pragma unroll
        for (int nf = 0; nf < 2; ++nf)
            bfr[nf] = *(const short8_t*)(sBT + (wn * 32 + nf * 16 + l15) * LB + k0 + kk);
        #pragma unroll
        for (int mf = 0; mf < 4; ++mf) {
            short8_t a = *(const short8_t*)(sA + (wm * 64 + mf * 16 + l15) * 40 + kk);
            acc[mf][0] = __builtin_amdgcn_mfma_f32_16x16x32_bf16(a, bfr[0], acc[mf][0], 0, 0, 0);
            acc[mf][1] = __builtin_amdgcn_mfma_f32_16x16x32_bf16(a, bfr[1], acc[mf][1], 0, 0, 0);
        }
    }

    #pragma unroll
    for (int nf = 0; nf < 2; ++nf) {
        int col = n0 + wn * 32 + nf * 16 + l15;
        float bcol = bias[col];
        #pragma unroll
        for (int mf = 0; mf < 4; ++mf) {
            int rowb = bm0 + wm * 64 + mf * 16 + (lane >> 4) * 4;
            #pragma unroll
            for (int i = 0; i < 4; ++i) {
                int r = rowb + i;
                if (r >= M) continue;
                float v = acc[mf][nf][i] + bcol;
                v = (v > 0.f) ? v : 0.01f * v;
                if (OBF) ((unsigned short*)out)[(size_t)r * N + col] = f2b(v);
                else     ((float*)out)[(size_t)r * N + col] = v;
            }
        }
    }
}

extern "C" void kernel_launch(void* const* d_in, const int* in_sizes, int n_in,
                              void* d_out, int out_size, void* d_ws, size_t ws_size,
                              hipStream_t stream) {
    const float* x_metric = (const float*)d_in[0];
    const float* x_alert  = (const float*)d_in[1];
    const float* w_corr   = (const float*)d_in[2];
    const float* w_cause  = (const float*)d_in[3];
    const int* src_corr   = (const int*)d_in[4];
    const int* dst_corr   = (const int*)d_in[5];
    const int* src_cause  = (const int*)d_in[6];
    const int* dst_cause  = (const int*)d_in[7];
    const float* Wr_c0 = (const float*)d_in[8];
    const float* br_c0 = (const float*)d_in[9];
    const float* Wo_c0 = (const float*)d_in[10];
    const float* Wr_k0 = (const float*)d_in[11];
    const float* br_k0 = (const float*)d_in[12];
    const float* Wo_k0 = (const float*)d_in[13];
    // d_in[14..16] dead (layer-1 metric update unused)
    const float* Wr_k1 = (const float*)d_in[17];
    const float* br_k1 = (const float*)d_in[18];
    const float* Wo_k1 = (const float*)d_in[19];

    // ---- workspace layout, ALL offsets in 4-byte units, disjoint extents ----
    // xh_m   [0,          3,200,000)   N_M*64 bf16 = 3.2M units
    // xh_a   [3,200,000,  3,840,000)   N_A*64 bf16
    // wb     [3,840,000,  3,889,152)   98304 bf16   (pad to 3,900,000)
    // corr_rowptr  [3,900,000, 4,000,001)  pad 4,000,016
    // cause_rowptr [4,000,016, 4,020,017)  pad 4,020,032
    // corr_part    [4,020,032, 4,020,096)
    // cause_part   [4,020,096, 4,020,160)
    // corr_cursor  [4,020,160, 4,120,160)  } one
    // cause_cursor [4,120,160, 4,140,160)  } memset
    // gcur_c       [4,140,160, 4,140,168)  } (120,016 ints)
    // gcur_k       [4,140,168, 4,140,176)  }
    // corr_sw  [4,140,176,  7,340,176)   E_C int2
    // cause_sw [7,340,176,  8,940,176)   E_K int2
    // buckets (dead after fill_bkt):
    //   bkt_c_dst [ 8,940,176, 10,605,712)
    //   bkt_c_sw  [10,605,712, 13,936,784)
    //   bkt_k_dst [13,936,784, 14,802,320)
    //   bkt_k_sw  [14,802,320, 16,533,392)
    // post-build overlay (written only after buckets dead):
    //   aggm  [ 8,940,176, 12,140,176)   N_M*64 bf16 = 3.2M units
    //   aggk0 [12,140,176, 12,780,176)   N_A*64 bf16
    //   xm0h  [12,780,176, 19,180,176)   N_M*128 bf16 = 6.4M units
    //   xa0h  [19,180,176, 20,460,176)   N_A*128 bf16
    //   aggk1 [20,460,176, 21,740,176)   N_A*128 bf16   => 86.96 MB total
    float* ws = (float*)d_ws;
    unsigned short* xh_m = (unsigned short*)(ws);
    unsigned short* xh_a = (unsigned short*)(ws + 3200000);
    unsigned short* wb   = (unsigned short*)(ws + 3840000);
    int*  corr_rowptr  = (int*)(ws + 3900000);
    int*  cause_rowptr = (int*)(ws + 4000016);
    int*  corr_part    = (int*)(ws + 4020032);
    int*  cause_part   = (int*)(ws + 4020096);
    int*  corr_cursor  = (int*)(ws + 4020160);
    int*  cause_cursor = (int*)(ws + 4120160);
    int*  gcur_c       = (int*)(ws + 4140160);
    int*  gcur_k       = (int*)(ws + 4140168);
    int2* corr_sw      = (int2*)(ws + 4140176);
    int2* cause_sw     = (int2*)(ws + 7340176);
    int*  bkt_c_dst = (int*)(ws + 8940176);
    int2* bkt_c_sw  = (int2*)(ws + 10605712);
    int*  bkt_k_dst = (int*)(ws + 13936784);
    int2* bkt_k_sw  = (int2*)(ws + 14802320);
    unsigned short* aggm  = (unsigned short*)(ws + 8940176);
    unsigned short* aggk0 = (unsigned short*)(ws + 12140176);
    unsigned short* xm0h  = (unsigned short*)(ws + 12780176);
    unsigned short* xa0h  = (unsigned short*)(ws + 19180176);
    unsigned short* aggk1 = (unsigned short*)(ws + 20460176);

    const unsigned short* Wb_rc0 = wb;
    const unsigned short* Wb_oc0 = wb + 8192;
    const unsigned short* Wb_rk0 = wb + 16384;
    const unsigned short* Wb_ok0 = wb + 24576;
    const unsigned short* Wb_rk1 = wb + 32768;
    const unsigned short* Wb_ok1 = wb + 65536;

    const int corr_chunks  = (E_C + CH - 1) / CH;   // 782
    const int cause_chunks = (E_K + CH - 1) / CH;   // 391
    const int corr_P  = (N_M + CH - 1) / CH;        // 49
    const int cause_P = (N_A + CH - 1) / CH;        // 10
    const int corr_bsegs  = (CAP_C + CH - 1) / CH;  // 102
    const int cause_bsegs = (CAP_K + CH - 1) / CH;  // 53

    // ---- casts ----
    cast_f32_bf16<<<(N_M * 64 / 4 + 255) / 256, 256, 0, stream>>>(x_metric, xh_m, N_M * 64);
    cast_f32_bf16<<<(N_A * 64 / 4 + 255) / 256, 256, 0, stream>>>(x_alert, xh_a, N_A * 64);
    cast_weights<<<96, 256, 0, stream>>>(Wr_c0, Wo_c0, Wr_k0, Wo_k0, Wr_k1, Wo_k1, wb);

    // ---- CSR build: bucket -> hist -> scan -> fill ----
    hipMemsetAsync(corr_cursor, 0, (size_t)(N_M + N_A + 16) * 4, stream);
    bucket_pass_t<<<corr_chunks, 256, 0, stream>>>(dst_corr, src_corr, w_corr,
                                                   bkt_c_dst, bkt_c_sw, gcur_c,
                                                   E_C, N_M / 8, CAP_C);
    bucket_pass_t<<<cause_chunks, 256, 0, stream>>>(dst_cause, src_cause, w_cause,
                                                    bkt_k_dst, bkt_k_sw, gcur_k,
                                                    E_K, N_A / 8, CAP_K);
    hist_bkt<<<corr_bsegs * 8, 256, 0, stream>>>(bkt_c_dst, gcur_c, corr_cursor, CAP_C);
    hist_bkt<<<cause_bsegs * 8, 256, 0, stream>>>(bkt_k_dst, gcur_k, cause_cursor, CAP_K);
    scan_p1<<<corr_P, 256, 0, stream>>>(corr_cursor, corr_part, N_M);
    scan_p1<<<cause_P, 256, 0, stream>>>(cause_cursor, cause_part, N_A);
    scan_p2<<<1, 64, 0, stream>>>(corr_part, corr_rowptr + N_M, corr_P);
    scan_p2<<<1, 64, 0, stream>>>(cause_part, cause_rowptr + N_A, cause_P);
    scan_p3<<<corr_P, 256, 0, stream>>>(corr_cursor, corr_part, corr_rowptr, corr_cursor, N_M);
    scan_p3<<<cause_P, 256, 0, stream>>>(cause_cursor, cause_part, cause_rowptr, cause_cursor, N_A);
    fill_bkt<<<corr_bsegs * 8, 256, 0, stream>>>(bkt_c_dst, bkt_c_sw, gcur_c,
                                                 corr_cursor, corr_sw, CAP_C);
    fill_bkt<<<cause_bsegs * 8, 256, 0, stream>>>(bkt_k_dst, bkt_k_sw, gcur_k,
                                                  cause_cursor, cause_sw, CAP_K);

    // ---- layer 0 aggregations (buckets dead from here on) ----
    agg_sum_d64_b<<<(N_M + 3) / 4, 256, 0, stream>>>(xh_m, corr_sw, corr_rowptr, aggm, N_M);
    agg_max_d64_b<<<(N_A + 3) / 4, 256, 0, stream>>>(xh_m, cause_sw, cause_rowptr, aggk0, N_A);

    // ---- layer 0 GEMMs (MFMA) ----
    {   dim3 grid(128 / 64, (N_A + 127) / 128);
        dual_gemm_mfma<64, 64, true><<<grid, 256, 0, stream>>>(
            aggk0, xh_a, Wb_rk0, Wb_ok0, br_k0, xa0h, N_A, 128);
    }
    {   dim3 grid(128 / 64, (N_M + 127) / 128);
        dual_gemm_mfma<64, 64, true><<<grid, 256, 0, stream>>>(
            aggm, xh_m, Wb_rc0, Wb_oc0, br_c0, xm0h, N_M, 128);
    }

    // ---- layer 1 (alert path only) ----
    agg_max_d128_b<<<(N_A + 3) / 4, 256, 0, stream>>>(xm0h, cause_sw, cause_rowptr, aggk1, N_A);
    {   dim3 grid(256 / 64, (N_A + 127) / 128);
        dual_gemm_mfma<128, 128, false><<<grid, 256, 0, stream>>>(
            aggk1, xa0h, Wb_rk1, Wb_ok1, br_k1, (float*)d_out, N_A, 256);
    }
}